// Round 9
// baseline (2047.122 us; speedup 1.0000x reference)
//
#include <hip/hip_runtime.h>
#include <hip/hip_bf16.h>
#include <math.h>

typedef __bf16 bf16x8 __attribute__((ext_vector_type(8)));
typedef float f32x4 __attribute__((ext_vector_type(4)));

#define GLOBAL_LOAD_LDS16(gptr, lptr) \
  __builtin_amdgcn_global_load_lds((const __attribute__((address_space(1))) void*)(gptr), \
                                   (__attribute__((address_space(3))) void*)(lptr), 16, 0, 0)

// XCD-aware bijective remap (m204) + GROUP_M=8 grouping: blocks resident on
// one XCD get a contiguous 2D patch of tiles -> A/B panels become L2 hits.
__device__ __forceinline__ void tile_map(int bid, int nbx, int nby, int& bx, int& by) {
  int nwg = nbx * nby;
  int q = nwg >> 3, r = nwg & 7;
  int xcd = bid & 7, orig = bid >> 3;
  int wgid = (xcd < r ? xcd * (q + 1) : r * (q + 1) + (xcd - r) * q) + orig;
  int per = nbx << 3;               // 8 M-rows per group
  int grp = wgid / per;
  int rem = wgid - grp * per;
  int g0 = grp << 3;
  int gm = nby - g0; if (gm > 8) gm = 8;
  by = g0 + rem % gm;               // m-fastest within group (B-panel reuse)
  bx = rem / gm;
}

// ---------------------------------------------------------------------------
// WIDE-TILE bf16 GEMM: C[M,N] = A[M,K] @ BT[N,K]^T. 128x256 tile, BK=64,
// single-buffered (48KB LDS), 4 waves, wave tile 64x128 (acc[4][8]).
// Rationale (r8 counters): at 64x64 wave tiles LDS reads (16 b128 / 32 MFMA /
// wave-iter) exceed the LDS port; widening to 64x128 cuts reads/FLOP and
// staging bytes/FLOP by 25%. 2 blocks/CU (= the 8 waves/CU we measure anyway).
// Chunk xor-swizzle c^(r&7), stage source pre-swizzled, LDS dest linear.
// MODE 0: GEMM1a split epilogue (xBC bf16 stride 4352 | dt fp32 via out2),
//         B rows clamped at N-1, stores masked (N=4416, 18 n-tiles)
// MODE 2: z-GEMM + gate: g = y*silu(z)*nw in-place into yio; ssum[t] += yf^2
// ---------------------------------------------------------------------------
template<int MODE>
__global__ __launch_bounds__(256, 2)
void gemmw_kernel(const __bf16* __restrict__ A, const __bf16* __restrict__ BT,
                  int M, int N, int K, int Ktot,
                  __bf16* __restrict__ out0, float* __restrict__ out2,
                  __bf16* yio, float* __restrict__ ssum,
                  const float* __restrict__ nwp)
{
  __shared__ __align__(16) __bf16 As[128 * 64];   // 16KB
  __shared__ __align__(16) __bf16 Bs[256 * 64];   // 32KB
  const int tid  = threadIdx.x;
  const int wave = tid >> 6, lane = tid & 63;
  const int quad = lane >> 4, l16 = lane & 15;
  const int wm = (wave & 1) * 64;                 // m band (2)
  const int wn = (wave >> 1) * 128;               // n band (2)
  int bx, by;
  tile_map(blockIdx.y * gridDim.x + blockIdx.x, gridDim.x, gridDim.y, bx, by);
  const int mBase = by * 128;
  const int nBase = bx * 256;

  f32x4 acc[4][8] = {};

  for (int k0 = 0; k0 < K; k0 += 64) {
    __syncthreads();                          // previous iter's ds_reads done
#pragma unroll
    for (int rd = 0; rd < 4; ++rd) {          // A: 128 rows
      int p = rd * 256 + tid;
      int row = p >> 3;
      int lc  = (p & 7) ^ (row & 7);
      const __bf16* gpA = A + (size_t)(mBase + row) * Ktot + k0 + lc * 8;
      GLOBAL_LOAD_LDS16(gpA, As + rd * 2048 + wave * 512);
    }
#pragma unroll
    for (int rd = 0; rd < 8; ++rd) {          // B: 256 rows
      int p = rd * 256 + tid;
      int row = p >> 3;                       // 0..255
      int lc  = (p & 7) ^ (row & 7);
      int gr = nBase + row; if (gr >= N) gr = N - 1;   // clamp (stores masked)
      const __bf16* gpB = BT + (size_t)gr * Ktot + k0 + lc * 8;
      GLOBAL_LOAD_LDS16(gpB, Bs + rd * 2048 + wave * 512);
    }
    __syncthreads();                          // drains vmcnt (compiler-emitted)
#pragma unroll
    for (int ks = 0; ks < 2; ++ks) {
      bf16x8 af[4], bfr[8];
#pragma unroll
      for (int i = 0; i < 4; ++i) {
        int r = wm + i * 16 + l16;
        af[i] = *(const bf16x8*)(As + (r << 6) + (((ks * 4 + quad) ^ (r & 7)) << 3));
      }
#pragma unroll
      for (int j = 0; j < 8; ++j) {
        int rb = wn + j * 16 + l16;
        bfr[j] = *(const bf16x8*)(Bs + (rb << 6) + (((ks * 4 + quad) ^ (rb & 7)) << 3));
      }
#pragma unroll
      for (int i = 0; i < 4; ++i)
#pragma unroll
        for (int j = 0; j < 8; ++j)
          acc[i][j] = __builtin_amdgcn_mfma_f32_16x16x32_bf16(af[i], bfr[j], acc[i][j], 0, 0, 0);
    }
  }

  // epilogue: C/D layout col = lane&15, row = quad*4 + r
  if (MODE == 2) {
    for (int i = 0; i < 4; ++i)
      for (int r = 0; r < 4; ++r) {
        int row = mBase + wm + i * 16 + quad * 4 + r;
        float sq = 0.f;
        for (int j = 0; j < 8; ++j) {
          int col = nBase + wn + j * 16 + l16;
          float v = acc[i][j][r];
          size_t idx = (size_t)row * 4096 + col;
          float y0 = (float)yio[idx];
          float zg = v / (1.f + expf(-v));    // silu(z)
          float yf = y0 * zg;
          yio[idx] = (__bf16)(yf * nwp[col]);
          sq += yf * yf;
        }
        for (int m = 1; m < 16; m <<= 1) sq += __shfl_xor(sq, m, 64);
        if (l16 == 0) atomicAdd(&ssum[row], sq);
      }
  } else {
    for (int i = 0; i < 4; ++i) {
      int rowl = wm + i * 16 + quad * 4;
      for (int j = 0; j < 8; ++j) {
        int col = nBase + wn + j * 16 + l16;
        for (int r = 0; r < 4; ++r) {
          float v = acc[i][j][r];
          int row = mBase + rowl + r;
          if (col < 4352)       out0[(size_t)row * 4352 + col]        = (__bf16)v;
          else if (col < 4416)  out2[(size_t)row * 64 + (col - 4352)] = v;
        }
      }
    }
  }
}

// ---------------------------------------------------------------------------
// bf16 GEMM 128x128, BK=64 (proven r6: 92us): used for GEMM2 (N=2048 needs
// the narrower tile for grid size 512 = 2/CU).
// MODE 3: final GEMM, rows scaled by rsqrt(ssum/4096+eps), plain fp32 store
// ---------------------------------------------------------------------------
template<int MODE>
__global__ __launch_bounds__(256, 3)
void gemm_kernel(const __bf16* __restrict__ A, const __bf16* __restrict__ BT,
                 int M, int N, int K, int Ktot,
                 __bf16* __restrict__ out0, float* __restrict__ out2,
                 float* __restrict__ ssum)
{
  __shared__ __align__(16) __bf16 As[128 * 64];
  __shared__ __align__(16) __bf16 Bs[128 * 64];
  const int tid  = threadIdx.x;
  const int wave = tid >> 6, lane = tid & 63;
  const int quad = lane >> 4, l16 = lane & 15;
  int bx, by;
  tile_map(blockIdx.y * gridDim.x + blockIdx.x, gridDim.x, gridDim.y, bx, by);
  const int mBase = by * 128;
  const int nBase = bx * 128;
  const int wm = (wave & 1) * 64;
  const int wn = (wave >> 1) * 64;

  f32x4 acc[4][4] = {};

  for (int k0 = 0; k0 < K; k0 += 64) {
    __syncthreads();
    for (int rd = 0; rd < 4; ++rd) {
      int p = rd * 256 + tid;
      int row = p >> 3;
      int lc  = (p & 7) ^ (row & 7);
      const __bf16* gpA = A + (size_t)(mBase + row) * Ktot + k0 + lc * 8;
      GLOBAL_LOAD_LDS16(gpA, As + rd * 2048 + wave * 512);
      int gr = nBase + row; if (gr >= N) gr = N - 1;
      const __bf16* gpB = BT + (size_t)gr * Ktot + k0 + lc * 8;
      GLOBAL_LOAD_LDS16(gpB, Bs + rd * 2048 + wave * 512);
    }
    __syncthreads();
#pragma unroll
    for (int ks = 0; ks < 2; ++ks) {
      bf16x8 af[4], bfr[4];
#pragma unroll
      for (int i = 0; i < 4; ++i) {
        int r = wm + i * 16 + l16;
        af[i]  = *(const bf16x8*)(As + (r << 6) + (((ks * 4 + quad) ^ (r & 7)) << 3));
        int rb = wn + i * 16 + l16;
        bfr[i] = *(const bf16x8*)(Bs + (rb << 6) + (((ks * 4 + quad) ^ (rb & 7)) << 3));
      }
#pragma unroll
      for (int i = 0; i < 4; ++i)
#pragma unroll
        for (int j = 0; j < 4; ++j)
          acc[i][j] = __builtin_amdgcn_mfma_f32_16x16x32_bf16(af[i], bfr[j], acc[i][j], 0, 0, 0);
    }
  }

  // MODE 3 epilogue
  float rs[4][4];
  for (int i = 0; i < 4; ++i)
    for (int r = 0; r < 4; ++r) {
      int row = mBase + wm + i * 16 + quad * 4 + r;
      rs[i][r] = rsqrtf(ssum[row] / 4096.f + 1e-5f);
    }
  for (int i = 0; i < 4; ++i) {
    int rowl = wm + i * 16 + quad * 4;
    for (int j = 0; j < 4; ++j) {
      int col = nBase + wn + j * 16 + l16;
      for (int r = 0; r < 4; ++r) {
        int row = mBase + rowl + r;
        float o = acc[i][j][r] * rs[i][r];
        o = (o == o && fabsf(o) < 1e30f) ? o : 0.f;
        out2[(size_t)row * N + col] = o;
      }
    }
  }
}

// ---------------------------------------------------------------------------
// fp32 -> bf16 cast: vector f32x4 loads + one bf16x8 store
// ---------------------------------------------------------------------------
__global__ __launch_bounds__(256)
void cast_kernel(const float* __restrict__ in, __bf16* __restrict__ out)
{
  size_t g = ((size_t)blockIdx.x * 256 + threadIdx.x) * 8;
  f32x4 a = *(const f32x4*)(in + g);
  f32x4 b = *(const f32x4*)(in + g + 4);
  bf16x8 v;
  for (int j = 0; j < 4; ++j) { v[j] = (__bf16)a[j]; v[4 + j] = (__bf16)b[j]; }
  *(bf16x8*)(out + g) = v;
}

// ---------------------------------------------------------------------------
// fp32 transpose+cast: out[c][r] = (bf16)in[r][col0+c]. Vector loads/stores.
// ---------------------------------------------------------------------------
__global__ __launch_bounds__(256)
void transpose_kernel(const float* __restrict__ in, __bf16* __restrict__ out,
                      int R, int C, int col0)
{
  __shared__ __bf16 tile[64][72];
  const int tid = threadIdx.x;
  const int r0 = blockIdx.y * 64, c0 = blockIdx.x * 64;
  const int tr = tid >> 3, tc = (tid & 7) * 8;   // tr 0..31
  for (int hh = 0; hh < 2; ++hh) {
    const float* gp = in + (size_t)(r0 + tr + hh * 32) * C + col0 + c0 + tc;
    f32x4 a = *(const f32x4*)gp;
    f32x4 b = *(const f32x4*)(gp + 4);
    for (int j = 0; j < 4; ++j) {
      tile[tr + hh * 32][tc + j]     = (__bf16)a[j];
      tile[tr + hh * 32][tc + 4 + j] = (__bf16)b[j];
    }
  }
  __syncthreads();
  for (int hh = 0; hh < 2; ++hh) {
    __bf16* op = out + (size_t)(c0 + tr + hh * 32) * R + r0 + tc;
    bf16x8 o;
    for (int j = 0; j < 8; ++j) o[j] = tile[tc + j][tr + hh * 32];
    *(bf16x8*)op = o;
  }
}

// ---------------------------------------------------------------------------
// FUSED causal conv1d (K=4) + bias + SiLU + routing + transposes.
// Grid (68 c-tiles x 64 t-tiles), 64x64 tile per block, 2 rows/thread.
//  bx<64 : x-region -> xconv[t][c] AND xdtT[c][t] = x*dtp via LDS
//  bx=64,65: B-region -> Bmat[t][n] AND BTr[n][t] via LDS
//  bx=66,67: C-region -> Cmat[t][n]
// ---------------------------------------------------------------------------
__global__ __launch_bounds__(256)
void conv_fused_kernel(const __bf16* __restrict__ xBCraw, const float* __restrict__ conv_w,
                       const float* __restrict__ conv_b, const float* __restrict__ dtp,
                       __bf16* __restrict__ xconv, __bf16* __restrict__ xdtT,
                       __bf16* __restrict__ Bmat, __bf16* __restrict__ Cmat,
                       __bf16* __restrict__ BTr)
{
  __shared__ __bf16 tile[64][72];
  const int bx = blockIdx.x;                  // c-tile 0..67
  const int t0 = blockIdx.y * 64;
  const int tid = threadIdx.x;
  const int tr = tid >> 3, tc = (tid & 7) * 8;
  const int cc = bx * 64 + tc;                // global conv col

  float wgt[4][8], bias[8];
  {
    f32x4 b0 = *(const f32x4*)(conv_b + cc);
    f32x4 b1 = *(const f32x4*)(conv_b + cc + 4);
    for (int j = 0; j < 4; ++j) { bias[j] = b0[j]; bias[4 + j] = b1[j]; }
    for (int k = 0; k < 4; ++k) {
      f32x4 w0 = *(const f32x4*)(conv_w + (size_t)k * 4352 + cc);
      f32x4 w1 = *(const f32x4*)(conv_w + (size_t)k * 4352 + cc + 4);
      for (int j = 0; j < 4; ++j) { wgt[k][j] = w0[j]; wgt[k][4 + j] = w1[j]; }
    }
  }

  for (int hh = 0; hh < 2; ++hh) {
    int t = t0 + tr + hh * 32;
    float acc[8];
    for (int j = 0; j < 8; ++j) acc[j] = bias[j];
    for (int k = 0; k < 4; ++k) {
      int ts = t + k - 3;
      if (ts >= 0) {
        bf16x8 xv = *(const bf16x8*)(xBCraw + (size_t)ts * 4352 + cc);
        for (int j = 0; j < 8; ++j) acc[j] += (float)xv[j] * wgt[k][j];
      }
    }
    for (int j = 0; j < 8; ++j) { float v = acc[j]; acc[j] = v / (1.f + expf(-v)); }
    bf16x8 o;
    for (int j = 0; j < 8; ++j) o[j] = (__bf16)acc[j];
    if (bx < 64) {
      *(bf16x8*)(xconv + (size_t)t * 4096 + cc) = o;
      float ds = dtp[(size_t)t * 64 + bx];    // h == bx (tile 64-aligned)
      for (int j = 0; j < 8; ++j) tile[tr + hh * 32][tc + j] = (__bf16)(acc[j] * ds);
    } else if (bx < 66) {
      *(bf16x8*)(Bmat + (size_t)t * 128 + (cc - 4096)) = o;
      for (int j = 0; j < 8; ++j) tile[tr + hh * 32][tc + j] = o[j];
    } else {
      *(bf16x8*)(Cmat + (size_t)t * 128 + (cc - 4224)) = o;
    }
  }
  __syncthreads();
  if (bx < 64) {
    for (int hh = 0; hh < 2; ++hh) {
      __bf16* op = xdtT + (size_t)(bx * 64 + tr + hh * 32) * 4096 + t0 + tc;
      bf16x8 o;
      for (int j = 0; j < 8; ++j) o[j] = tile[tc + j][tr + hh * 32];
      *(bf16x8*)op = o;
    }
  } else if (bx < 66) {
    for (int hh = 0; hh < 2; ++hh) {
      __bf16* op = BTr + (size_t)((bx - 64) * 64 + tr + hh * 32) * 4096 + t0 + tc;
      bf16x8 o;
      for (int j = 0; j < 8; ++j) o[j] = tile[tc + j][tr + hh * 32];
      *(bf16x8*)op = o;
    }
  }
}

// ---------------------------------------------------------------------------
// dt = clip(softplus(dtraw + bias)); dA = dt*A; within-chunk inclusive cumsum.
// ---------------------------------------------------------------------------
__global__ __launch_bounds__(256)
void dt_cumsum_kernel(const float* __restrict__ dtraw, const float* __restrict__ dt_bias,
                      const float* __restrict__ A_log, float* __restrict__ dtp,
                      float* __restrict__ csbuf)
{
  int h = blockIdx.x, cch = blockIdx.y, i = threadIdx.x;
  int t = cch * 256 + i;
  float x = dtraw[(size_t)t * 64 + h] + dt_bias[h];
  float sp = (x > 20.f) ? x : log1pf(expf(x));
  sp = fminf(fmaxf(sp, 0.f), 100.f);
  dtp[(size_t)t * 64 + h] = sp;
  float Ah = -expf(A_log[h]);
  __shared__ float s[256];
  s[i] = sp * Ah;
  __syncthreads();
  for (int off = 1; off < 256; off <<= 1) {
    float add = (i >= off) ? s[i - off] : 0.f;
    __syncthreads();
    s[i] += add;
    __syncthreads();
  }
  csbuf[(size_t)h * 4096 + t] = s[i];
}

// ---------------------------------------------------------------------------
// raw chunk scores[c][l][s] = sum_n C[l,n] B[s,n]
// ---------------------------------------------------------------------------
__global__ __launch_bounds__(256)
void scores_kernel(const __bf16* __restrict__ Cmat, const __bf16* __restrict__ Bmat,
                   __bf16* __restrict__ scores)
{
  const int c = blockIdx.x;
  const int lb = blockIdx.y * 128, sb = blockIdx.z * 128;
  const int tid = threadIdx.x, wave = tid >> 6, lane = tid & 63;
  const int quad = lane >> 4, l16 = lane & 15;
  const int wl = (wave & 1) * 64, ws = (wave >> 1) * 64;
  f32x4 acc[4][4] = {};
  for (int k = 0; k < 4; ++k) {
    bf16x8 af[4], bfr[4];
    for (int i = 0; i < 4; ++i) {
      int tl = c * 256 + lb + wl + i * 16 + l16;
      af[i] = *(const bf16x8*)(Cmat + (size_t)tl * 128 + k * 32 + quad * 8);
    }
    for (int j = 0; j < 4; ++j) {
      int ts = c * 256 + sb + ws + j * 16 + l16;
      bfr[j] = *(const bf16x8*)(Bmat + (size_t)ts * 128 + k * 32 + quad * 8);
    }
    for (int i = 0; i < 4; ++i)
      for (int j = 0; j < 4; ++j)
        acc[i][j] = __builtin_amdgcn_mfma_f32_16x16x32_bf16(af[i], bfr[j], acc[i][j], 0, 0, 0);
  }
  for (int i = 0; i < 4; ++i)
    for (int j = 0; j < 4; ++j) {
      int lrow = lb + wl + i * 16 + quad * 4;
      int scol = sb + ws + j * 16 + l16;
      for (int r = 0; r < 4; ++r)
        scores[((size_t)c * 256 + lrow + r) * 256 + scol] = (__bf16)acc[i][j][r];
    }
}

// ---------------------------------------------------------------------------
// chunk_states[c][h][p][n] = sum_l xdtT[h,p][l] * (B[l,n] * exp(cs_end - cs_l))
// ---------------------------------------------------------------------------
__global__ __launch_bounds__(256)
void states_kernel(const __bf16* __restrict__ xdtT, const __bf16* __restrict__ BTr,
                   const float* __restrict__ csbuf, __bf16* __restrict__ chunk_states)
{
  const int c = blockIdx.x, h = blockIdx.y;
  const int tid = threadIdx.x, wave = tid >> 6, lane = tid & 63;
  const int quad = lane >> 4, l16 = lane & 15;
  __shared__ float decay[256];
  {
    float cs_end = csbuf[(size_t)h * 4096 + c * 256 + 255];
    decay[tid] = expf(fminf(cs_end - csbuf[(size_t)h * 4096 + c * 256 + tid], 0.f));
  }
  __syncthreads();
  const int wn = wave * 32;
  f32x4 acc[4][2] = {};
  for (int k = 0; k < 8; ++k) {
    bf16x8 af[4], bfr[2];
    for (int i = 0; i < 4; ++i) {
      int p = i * 16 + l16;
      af[i] = *(const bf16x8*)(xdtT + (size_t)(h * 64 + p) * 4096 + c * 256 + k * 32 + quad * 8);
    }
    for (int j = 0; j < 2; ++j) {
      int n = wn + j * 16 + l16;
      bf16x8 raw = *(const bf16x8*)(BTr + (size_t)n * 4096 + c * 256 + k * 32 + quad * 8);
      bf16x8 sc;
      for (int jj = 0; jj < 8; ++jj)
        sc[jj] = (__bf16)((float)raw[jj] * decay[k * 32 + quad * 8 + jj]);
      bfr[j] = sc;
    }
    for (int i = 0; i < 4; ++i)
      for (int j = 0; j < 2; ++j)
        acc[i][j] = __builtin_amdgcn_mfma_f32_16x16x32_bf16(af[i], bfr[j], acc[i][j], 0, 0, 0);
  }
  for (int i = 0; i < 4; ++i)
    for (int j = 0; j < 2; ++j) {
      int p = i * 16 + quad * 4;
      int n = wn + j * 16 + l16;
      for (int r = 0; r < 4; ++r)
        chunk_states[(((size_t)c * 64 + h) * 64 + p + r) * 128 + n] = (__bf16)acc[i][j][r];
    }
}

// ---------------------------------------------------------------------------
// inter-chunk scan, IN-PLACE (states_in[c] overwrites chunk_states[c])
// ---------------------------------------------------------------------------
__global__ __launch_bounds__(256)
void scan_kernel(__bf16* states, const float* __restrict__ csbuf)
{
  size_t id = (size_t)blockIdx.x * 256 + threadIdx.x;  // 64*64*128
  int n = id & 127;
  int p = (int)((id >> 7) & 63);
  int h = (int)(id >> 13);
  float S = 0.f;
  for (int c = 0; c < 16; ++c) {
    size_t idx = (((size_t)c * 64 + h) * 64 + p) * 128 + n;
    float cst = (float)states[idx];
    states[idx] = (__bf16)S;
    float ce = csbuf[(size_t)h * 4096 + c * 256 + 255];
    S = S * expf(fminf(ce, 0.f)) + cst;
  }
}

// ---------------------------------------------------------------------------
// per (chunk, head): Y = exp(cs_l)*(C @ S_in^T) + (scores.decay.mask) @ xdt + x*D
// IN-PLACE: y holds xconv[t][hp] on entry; overwritten with the result.
// ---------------------------------------------------------------------------
__global__ __launch_bounds__(256)
void y_kernel(const __bf16* __restrict__ Cmat, const __bf16* __restrict__ states_in,
              const __bf16* __restrict__ scores, const __bf16* __restrict__ xdtT,
              const float* __restrict__ csbuf, const float* __restrict__ Dvec,
              __bf16* y)
{
  const int c = blockIdx.x, h = blockIdx.y;
  const int tid = threadIdx.x, wave = tid >> 6, lane = tid & 63;
  const int quad = lane >> 4, l16 = lane & 15;
  __shared__ float cs[256];
  cs[tid] = csbuf[(size_t)h * 4096 + c * 256 + tid];
  __syncthreads();
  const int wl = wave * 64;
  f32x4 acc[4][4] = {};

  // Y_off: A = C[l][n], B = states_in[c][h][p][n]
  for (int k = 0; k < 4; ++k) {
    bf16x8 af[4], bfr[4];
    for (int i = 0; i < 4; ++i) {
      int tl = c * 256 + wl + i * 16 + l16;
      af[i] = *(const bf16x8*)(Cmat + (size_t)tl * 128 + k * 32 + quad * 8);
    }
    for (int j = 0; j < 4; ++j) {
      int p = j * 16 + l16;
      bfr[j] = *(const bf16x8*)(states_in + (((size_t)c * 64 + h) * 64 + p) * 128 + k * 32 + quad * 8);
    }
    for (int i = 0; i < 4; ++i)
      for (int j = 0; j < 4; ++j)
        acc[i][j] = __builtin_amdgcn_mfma_f32_16x16x32_bf16(af[i], bfr[j], acc[i][j], 0, 0, 0);
  }
  for (int i = 0; i < 4; ++i)
    for (int r = 0; r < 4; ++r) {
      float sd = expf(fminf(cs[wl + i * 16 + quad * 4 + r], 0.f));
      for (int j = 0; j < 4; ++j) acc[i][j][r] *= sd;
    }
  // Y_diag: A = scores*decay*mask (built per fragment), B = xdtT
  for (int sb = 0; sb < 8; ++sb) {
    bf16x8 af[4], bfr[4];
    for (int i = 0; i < 4; ++i) {
      int lloc = wl + i * 16 + l16;
      bf16x8 raw = *(const bf16x8*)(scores + ((size_t)c * 256 + lloc) * 256 + sb * 32 + quad * 8);
      float csl = cs[lloc];
      bf16x8 w;
      for (int jj = 0; jj < 8; ++jj) {
        int s = sb * 32 + quad * 8 + jj;
        float e = expf(fminf(csl - cs[s], 0.f));
        float v = (s <= lloc) ? (float)raw[jj] * e : 0.f;
        w[jj] = (__bf16)v;
      }
      af[i] = w;
    }
    for (int j = 0; j < 4; ++j) {
      int p = j * 16 + l16;
      bfr[j] = *(const bf16x8*)(xdtT + (size_t)(h * 64 + p) * 4096 + c * 256 + sb * 32 + quad * 8);
    }
    for (int i = 0; i < 4; ++i)
      for (int j = 0; j < 4; ++j)
        acc[i][j] = __builtin_amdgcn_mfma_f32_16x16x32_bf16(af[i], bfr[j], acc[i][j], 0, 0, 0);
  }
  // epilogue: read x (in-place), add x*D, store
  float Dh = Dvec[h];
  for (int i = 0; i < 4; ++i)
    for (int r = 0; r < 4; ++r) {
      int tl = c * 256 + wl + i * 16 + quad * 4 + r;
      for (int j = 0; j < 4; ++j) {
        int p = j * 16 + l16;
        size_t idx = (size_t)tl * 4096 + h * 64 + p;
        float xv = (float)y[idx];
        y[idx] = (__bf16)(acc[i][j][r] + xv * Dh);
      }
    }
}

// ---------------------------------------------------------------------------
extern "C" void kernel_launch(void* const* d_in, const int* in_sizes, int n_in,
                              void* d_out, int out_size, void* d_ws, size_t ws_size,
                              hipStream_t stream)
{
  const float* hs      = (const float*)d_in[0];
  const float* W_in    = (const float*)d_in[1];
  const float* conv_w  = (const float*)d_in[2];
  const float* conv_b  = (const float*)d_in[3];
  const float* dt_bias = (const float*)d_in[4];
  const float* A_log   = (const float*)d_in[5];
  const float* Dv      = (const float*)d_in[6];
  const float* nw      = (const float*)d_in[7];
  const float* W_out   = (const float*)d_in[8];
  float* out = (float*)d_out;

  // Layout ~94.4 MB + d_out as xdtT scratch (dead before GEMM2 writes out).
  char* base = (char*)d_ws;
  const size_t P0 = 0;
  const size_t P1 = 35651584;
  const size_t P2 = 69206016;
  const size_t P3 = 77611008;

  __bf16* xBCraw  = (__bf16*)(base + P0);
  __bf16* states  = (__bf16*)(base + P0);
  __bf16* wTz     = (__bf16*)(base + P0);
  __bf16* wT_out  = (__bf16*)(base + P0 + 16777216);
  __bf16* wTa     = (__bf16*)(base + P1);
  __bf16* xconv   = (__bf16*)(base + P1);
  __bf16* Bmat    = (__bf16*)(base + P2);
  __bf16* Cmat    = (__bf16*)(base + P2 + 1048576);
  __bf16* BTr     = (__bf16*)(base + P2 + 2097152);
  float*  dtp     = (float*) (base + P2 + 3145728);
  float*  csbuf   = (float*) (base + P2 + 4194304);
  __bf16* scores  = (__bf16*)(base + P2 + 5242880);
  float*  dtraw   = (float*) (base + P2 + 7340032);
  float*  ssum    = (float*) (base + P2 + 8388608);   // 16KB
  __bf16* hs16    = (__bf16*)(base + P3);
  __bf16* xdtT    = (__bf16*)d_out;                    // 33.55MB scratch

  hipMemsetAsync(ssum, 0, 4096 * sizeof(float), stream);
  // 0. cast hs fp32 -> bf16
  cast_kernel<<<4096, 256, 0, stream>>>(hs, hs16);
  // 1. transpose+cast W_in cols [4096,8512) -> wTa[4416][2048]
  transpose_kernel<<<dim3(69, 32), 256, 0, stream>>>(W_in, wTa, 2048, 8512, 4096);
  // 2. GEMM1a wide-tile: xBC + dtraw (18 n-tiles of 256, masked edge)
  gemmw_kernel<0><<<dim3(18, 32), 256, 0, stream>>>(hs16, wTa, 4096, 4416, 2048, 2048,
                                                    xBCraw, dtraw, nullptr, nullptr, nullptr);
  // 3. dt softplus + cumsum (before conv: conv needs dtp)
  dt_cumsum_kernel<<<dim3(64, 16), 256, 0, stream>>>(dtraw, dt_bias, A_log, dtp, csbuf);
  // 4. FUSED conv + SiLU + xdtT/BTr transposes
  conv_fused_kernel<<<dim3(68, 64), 256, 0, stream>>>(xBCraw, conv_w, conv_b, dtp,
                                                      xconv, xdtT, Bmat, Cmat, BTr);
  // 5. chunk score matrices
  scores_kernel<<<dim3(16, 2, 2), 256, 0, stream>>>(Cmat, Bmat, scores);
  // 6. per-chunk states -> P0 (xBCraw dead)
  states_kernel<<<dim3(16, 64), 256, 0, stream>>>(xdtT, BTr, csbuf, states);
  // 7. inter-chunk scan in-place
  scan_kernel<<<2048, 256, 0, stream>>>(states, csbuf);
  // 8. y in-place over xconv
  y_kernel<<<dim3(16, 64), 256, 0, stream>>>(Cmat, states, scores, xdtT, csbuf, Dv, xconv);
  // 9. transpose+cast W_in cols [0,4096) -> wTz (states dead)
  transpose_kernel<<<dim3(64, 32), 256, 0, stream>>>(W_in, wTz, 2048, 8512, 0);
  // 10. z-GEMM wide-tile + gate, in-place on xconv, ssum
  gemmw_kernel<2><<<dim3(16, 32), 256, 0, stream>>>(hs16, wTz, 4096, 4096, 2048, 2048,
                                                    nullptr, nullptr, xconv, ssum, nw);
  // 11. transpose+cast W_out -> wT_out
  transpose_kernel<<<dim3(32, 64), 256, 0, stream>>>(W_out, wT_out, 4096, 2048, 0);
  // 12. GEMM2 128x128: plain fp32 store, per-row rsqrt scale (xdtT dead -> out)
  gemm_kernel<3><<<dim3(16, 32, 1), 256, 0, stream>>>(xconv, wT_out, 4096, 2048, 4096, 4096,
                                                      nullptr, out, ssum);
}

// Round 10
// 579.639 us; speedup vs baseline: 3.5317x; 3.5317x over previous
//
#include <hip/hip_runtime.h>
#include <hip/hip_bf16.h>
#include <math.h>

typedef __bf16 bf16x8 __attribute__((ext_vector_type(8)));
typedef float f32x4 __attribute__((ext_vector_type(4)));

#define GLOBAL_LOAD_LDS16(gptr, lptr) \
  __builtin_amdgcn_global_load_lds((const __attribute__((address_space(1))) void*)(gptr), \
                                   (__attribute__((address_space(3))) void*)(lptr), 16, 0, 0)

// XCD-aware bijective remap (m204) + GROUP_M=8 grouping: blocks resident on
// one XCD get a contiguous 2D patch of tiles -> A/B panels become L2 hits.
__device__ __forceinline__ void tile_map(int bid, int nbx, int nby, int& bx, int& by) {
  int nwg = nbx * nby;
  int q = nwg >> 3, r = nwg & 7;
  int xcd = bid & 7, orig = bid >> 3;
  int wgid = (xcd < r ? xcd * (q + 1) : r * (q + 1) + (xcd - r) * q) + orig;
  int per = nbx << 3;               // 8 M-rows per group
  int grp = wgid / per;
  int rem = wgid - grp * per;
  int g0 = grp << 3;
  int gm = nby - g0; if (gm > 8) gm = 8;
  by = g0 + rem % gm;               // m-fastest within group (B-panel reuse)
  bx = rem / gm;
}

// ---------------------------------------------------------------------------
// WIDE-TILE bf16 GEMM: C[M,N] = A[M,K] @ BT[N,K]^T. 128x256 tile, BK=64,
// single-buffered (48KB LDS), 4 waves, wave tile 64x128 (acc[4][8]).
// r9 POST-MORTEM: epilogue loops were left rolled -> acc[fi][j][r] was
// runtime-indexed -> WHOLE acc array demoted to scratch (rule #20) -> 4.8GB
// scratch writes/dispatch, 17x slowdown. Fix: #pragma unroll on EVERY loop
// that indexes acc, so all accesses are compile-time-constant.
// MODE 0: GEMM1a split epilogue (xBC bf16 stride 4352 | dt fp32 via out2),
//         B rows clamped at N-1, stores masked (N=4416, 18 n-tiles)
// MODE 2: z-GEMM + gate: g = y*silu(z)*nw in-place into yio; ssum[t] += yf^2
// ---------------------------------------------------------------------------
template<int MODE>
__global__ __launch_bounds__(256, 2)
void gemmw_kernel(const __bf16* __restrict__ A, const __bf16* __restrict__ BT,
                  int M, int N, int K, int Ktot,
                  __bf16* __restrict__ out0, float* __restrict__ out2,
                  __bf16* yio, float* __restrict__ ssum,
                  const float* __restrict__ nwp)
{
  __shared__ __align__(16) __bf16 As[128 * 64];   // 16KB
  __shared__ __align__(16) __bf16 Bs[256 * 64];   // 32KB
  const int tid  = threadIdx.x;
  const int wave = tid >> 6, lane = tid & 63;
  const int quad = lane >> 4, l16 = lane & 15;
  const int wm = (wave & 1) * 64;                 // m band (2)
  const int wn = (wave >> 1) * 128;               // n band (2)
  int bx, by;
  tile_map(blockIdx.y * gridDim.x + blockIdx.x, gridDim.x, gridDim.y, bx, by);
  const int mBase = by * 128;
  const int nBase = bx * 256;

  f32x4 acc[4][8] = {};

  for (int k0 = 0; k0 < K; k0 += 64) {
    __syncthreads();                          // previous iter's ds_reads done
#pragma unroll
    for (int rd = 0; rd < 4; ++rd) {          // A: 128 rows
      int p = rd * 256 + tid;
      int row = p >> 3;
      int lc  = (p & 7) ^ (row & 7);
      const __bf16* gpA = A + (size_t)(mBase + row) * Ktot + k0 + lc * 8;
      GLOBAL_LOAD_LDS16(gpA, As + rd * 2048 + wave * 512);
    }
#pragma unroll
    for (int rd = 0; rd < 8; ++rd) {          // B: 256 rows
      int p = rd * 256 + tid;
      int row = p >> 3;                       // 0..255
      int lc  = (p & 7) ^ (row & 7);
      int gr = nBase + row; if (gr >= N) gr = N - 1;   // clamp (stores masked)
      const __bf16* gpB = BT + (size_t)gr * Ktot + k0 + lc * 8;
      GLOBAL_LOAD_LDS16(gpB, Bs + rd * 2048 + wave * 512);
    }
    __syncthreads();                          // drains vmcnt (compiler-emitted)
#pragma unroll
    for (int ks = 0; ks < 2; ++ks) {
      bf16x8 af[4], bfr[8];
#pragma unroll
      for (int i = 0; i < 4; ++i) {
        int r = wm + i * 16 + l16;
        af[i] = *(const bf16x8*)(As + (r << 6) + (((ks * 4 + quad) ^ (r & 7)) << 3));
      }
#pragma unroll
      for (int j = 0; j < 8; ++j) {
        int rb = wn + j * 16 + l16;
        bfr[j] = *(const bf16x8*)(Bs + (rb << 6) + (((ks * 4 + quad) ^ (rb & 7)) << 3));
      }
#pragma unroll
      for (int i = 0; i < 4; ++i)
#pragma unroll
        for (int j = 0; j < 8; ++j)
          acc[i][j] = __builtin_amdgcn_mfma_f32_16x16x32_bf16(af[i], bfr[j], acc[i][j], 0, 0, 0);
    }
  }

  // epilogue: C/D layout col = lane&15, row = quad*4 + r
  // ALL loops unrolled so acc indexing is compile-time-constant (rule #20).
  if (MODE == 2) {
#pragma unroll
    for (int i = 0; i < 4; ++i)
#pragma unroll
      for (int r = 0; r < 4; ++r) {
        int row = mBase + wm + i * 16 + quad * 4 + r;
        float sq = 0.f;
#pragma unroll
        for (int j = 0; j < 8; ++j) {
          int col = nBase + wn + j * 16 + l16;
          float v = acc[i][j][r];
          size_t idx = (size_t)row * 4096 + col;
          float y0 = (float)yio[idx];
          float zg = v / (1.f + expf(-v));    // silu(z)
          float yf = y0 * zg;
          yio[idx] = (__bf16)(yf * nwp[col]);
          sq += yf * yf;
        }
#pragma unroll
        for (int m = 1; m < 16; m <<= 1) sq += __shfl_xor(sq, m, 64);
        if (l16 == 0) atomicAdd(&ssum[row], sq);
      }
  } else {
#pragma unroll
    for (int i = 0; i < 4; ++i) {
      int rowl = wm + i * 16 + quad * 4;
#pragma unroll
      for (int j = 0; j < 8; ++j) {
        int col = nBase + wn + j * 16 + l16;
#pragma unroll
        for (int r = 0; r < 4; ++r) {
          float v = acc[i][j][r];
          int row = mBase + rowl + r;
          if (col < 4352)       out0[(size_t)row * 4352 + col]        = (__bf16)v;
          else if (col < 4416)  out2[(size_t)row * 64 + (col - 4352)] = v;
        }
      }
    }
  }
}

// ---------------------------------------------------------------------------
// bf16 GEMM 128x128, BK=64 (proven r6: 92us): used for GEMM2 (N=2048 needs
// the narrower tile for grid size 512 = 2/CU).
// MODE 3: final GEMM, rows scaled by rsqrt(ssum/4096+eps), plain fp32 store
// ---------------------------------------------------------------------------
template<int MODE>
__global__ __launch_bounds__(256, 3)
void gemm_kernel(const __bf16* __restrict__ A, const __bf16* __restrict__ BT,
                 int M, int N, int K, int Ktot,
                 __bf16* __restrict__ out0, float* __restrict__ out2,
                 float* __restrict__ ssum)
{
  __shared__ __align__(16) __bf16 As[128 * 64];
  __shared__ __align__(16) __bf16 Bs[128 * 64];
  const int tid  = threadIdx.x;
  const int wave = tid >> 6, lane = tid & 63;
  const int quad = lane >> 4, l16 = lane & 15;
  int bx, by;
  tile_map(blockIdx.y * gridDim.x + blockIdx.x, gridDim.x, gridDim.y, bx, by);
  const int mBase = by * 128;
  const int nBase = bx * 128;
  const int wm = (wave & 1) * 64;
  const int wn = (wave >> 1) * 64;

  f32x4 acc[4][4] = {};

  for (int k0 = 0; k0 < K; k0 += 64) {
    __syncthreads();
    for (int rd = 0; rd < 4; ++rd) {
      int p = rd * 256 + tid;
      int row = p >> 3;
      int lc  = (p & 7) ^ (row & 7);
      const __bf16* gpA = A + (size_t)(mBase + row) * Ktot + k0 + lc * 8;
      GLOBAL_LOAD_LDS16(gpA, As + rd * 2048 + wave * 512);
      int gr = nBase + row; if (gr >= N) gr = N - 1;
      const __bf16* gpB = BT + (size_t)gr * Ktot + k0 + lc * 8;
      GLOBAL_LOAD_LDS16(gpB, Bs + rd * 2048 + wave * 512);
    }
    __syncthreads();
#pragma unroll
    for (int ks = 0; ks < 2; ++ks) {
      bf16x8 af[4], bfr[4];
#pragma unroll
      for (int i = 0; i < 4; ++i) {
        int r = wm + i * 16 + l16;
        af[i]  = *(const bf16x8*)(As + (r << 6) + (((ks * 4 + quad) ^ (r & 7)) << 3));
        int rb = wn + i * 16 + l16;
        bfr[i] = *(const bf16x8*)(Bs + (rb << 6) + (((ks * 4 + quad) ^ (rb & 7)) << 3));
      }
#pragma unroll
      for (int i = 0; i < 4; ++i)
#pragma unroll
        for (int j = 0; j < 4; ++j)
          acc[i][j] = __builtin_amdgcn_mfma_f32_16x16x32_bf16(af[i], bfr[j], acc[i][j], 0, 0, 0);
    }
  }

  // MODE 3 epilogue
#pragma unroll
  for (int i = 0; i < 4; ++i) {
#pragma unroll
    for (int j = 0; j < 4; ++j) {
      int col = nBase + wn + j * 16 + l16;
#pragma unroll
      for (int r = 0; r < 4; ++r) {
        int row = mBase + wm + i * 16 + quad * 4 + r;
        float s = rsqrtf(ssum[row] / 4096.f + 1e-5f);
        float o = acc[i][j][r] * s;
        o = (o == o && fabsf(o) < 1e30f) ? o : 0.f;
        out2[(size_t)row * N + col] = o;
      }
    }
  }
}

// ---------------------------------------------------------------------------
// fp32 -> bf16 cast: vector f32x4 loads + one bf16x8 store
// ---------------------------------------------------------------------------
__global__ __launch_bounds__(256)
void cast_kernel(const float* __restrict__ in, __bf16* __restrict__ out)
{
  size_t g = ((size_t)blockIdx.x * 256 + threadIdx.x) * 8;
  f32x4 a = *(const f32x4*)(in + g);
  f32x4 b = *(const f32x4*)(in + g + 4);
  bf16x8 v;
  for (int j = 0; j < 4; ++j) { v[j] = (__bf16)a[j]; v[4 + j] = (__bf16)b[j]; }
  *(bf16x8*)(out + g) = v;
}

// ---------------------------------------------------------------------------
// fp32 transpose+cast: out[c][r] = (bf16)in[r][col0+c]. Vector loads/stores.
// ---------------------------------------------------------------------------
__global__ __launch_bounds__(256)
void transpose_kernel(const float* __restrict__ in, __bf16* __restrict__ out,
                      int R, int C, int col0)
{
  __shared__ __bf16 tile[64][72];
  const int tid = threadIdx.x;
  const int r0 = blockIdx.y * 64, c0 = blockIdx.x * 64;
  const int tr = tid >> 3, tc = (tid & 7) * 8;   // tr 0..31
  for (int hh = 0; hh < 2; ++hh) {
    const float* gp = in + (size_t)(r0 + tr + hh * 32) * C + col0 + c0 + tc;
    f32x4 a = *(const f32x4*)gp;
    f32x4 b = *(const f32x4*)(gp + 4);
    for (int j = 0; j < 4; ++j) {
      tile[tr + hh * 32][tc + j]     = (__bf16)a[j];
      tile[tr + hh * 32][tc + 4 + j] = (__bf16)b[j];
    }
  }
  __syncthreads();
  for (int hh = 0; hh < 2; ++hh) {
    __bf16* op = out + (size_t)(c0 + tr + hh * 32) * R + r0 + tc;
    bf16x8 o;
    for (int j = 0; j < 8; ++j) o[j] = tile[tc + j][tr + hh * 32];
    *(bf16x8*)op = o;
  }
}

// ---------------------------------------------------------------------------
// FUSED causal conv1d (K=4) + bias + SiLU + routing + transposes.
// Grid (68 c-tiles x 64 t-tiles), 64x64 tile per block, 2 rows/thread.
//  bx<64 : x-region -> xconv[t][c] AND xdtT[c][t] = x*dtp via LDS
//  bx=64,65: B-region -> Bmat[t][n] AND BTr[n][t] via LDS
//  bx=66,67: C-region -> Cmat[t][n]
// ---------------------------------------------------------------------------
__global__ __launch_bounds__(256)
void conv_fused_kernel(const __bf16* __restrict__ xBCraw, const float* __restrict__ conv_w,
                       const float* __restrict__ conv_b, const float* __restrict__ dtp,
                       __bf16* __restrict__ xconv, __bf16* __restrict__ xdtT,
                       __bf16* __restrict__ Bmat, __bf16* __restrict__ Cmat,
                       __bf16* __restrict__ BTr)
{
  __shared__ __bf16 tile[64][72];
  const int bx = blockIdx.x;                  // c-tile 0..67
  const int t0 = blockIdx.y * 64;
  const int tid = threadIdx.x;
  const int tr = tid >> 3, tc = (tid & 7) * 8;
  const int cc = bx * 64 + tc;                // global conv col

  float wgt[4][8], bias[8];
  {
    f32x4 b0 = *(const f32x4*)(conv_b + cc);
    f32x4 b1 = *(const f32x4*)(conv_b + cc + 4);
    for (int j = 0; j < 4; ++j) { bias[j] = b0[j]; bias[4 + j] = b1[j]; }
    for (int k = 0; k < 4; ++k) {
      f32x4 w0 = *(const f32x4*)(conv_w + (size_t)k * 4352 + cc);
      f32x4 w1 = *(const f32x4*)(conv_w + (size_t)k * 4352 + cc + 4);
      for (int j = 0; j < 4; ++j) { wgt[k][j] = w0[j]; wgt[k][4 + j] = w1[j]; }
    }
  }

  for (int hh = 0; hh < 2; ++hh) {
    int t = t0 + tr + hh * 32;
    float acc[8];
    for (int j = 0; j < 8; ++j) acc[j] = bias[j];
    for (int k = 0; k < 4; ++k) {
      int ts = t + k - 3;
      if (ts >= 0) {
        bf16x8 xv = *(const bf16x8*)(xBCraw + (size_t)ts * 4352 + cc);
        for (int j = 0; j < 8; ++j) acc[j] += (float)xv[j] * wgt[k][j];
      }
    }
    for (int j = 0; j < 8; ++j) { float v = acc[j]; acc[j] = v / (1.f + expf(-v)); }
    bf16x8 o;
    for (int j = 0; j < 8; ++j) o[j] = (__bf16)acc[j];
    if (bx < 64) {
      *(bf16x8*)(xconv + (size_t)t * 4096 + cc) = o;
      float ds = dtp[(size_t)t * 64 + bx];    // h == bx (tile 64-aligned)
      for (int j = 0; j < 8; ++j) tile[tr + hh * 32][tc + j] = (__bf16)(acc[j] * ds);
    } else if (bx < 66) {
      *(bf16x8*)(Bmat + (size_t)t * 128 + (cc - 4096)) = o;
      for (int j = 0; j < 8; ++j) tile[tr + hh * 32][tc + j] = o[j];
    } else {
      *(bf16x8*)(Cmat + (size_t)t * 128 + (cc - 4224)) = o;
    }
  }
  __syncthreads();
  if (bx < 64) {
    for (int hh = 0; hh < 2; ++hh) {
      __bf16* op = xdtT + (size_t)(bx * 64 + tr + hh * 32) * 4096 + t0 + tc;
      bf16x8 o;
      for (int j = 0; j < 8; ++j) o[j] = tile[tc + j][tr + hh * 32];
      *(bf16x8*)op = o;
    }
  } else if (bx < 66) {
    for (int hh = 0; hh < 2; ++hh) {
      __bf16* op = BTr + (size_t)((bx - 64) * 64 + tr + hh * 32) * 4096 + t0 + tc;
      bf16x8 o;
      for (int j = 0; j < 8; ++j) o[j] = tile[tc + j][tr + hh * 32];
      *(bf16x8*)op = o;
    }
  }
}

// ---------------------------------------------------------------------------
// dt = clip(softplus(dtraw + bias)); dA = dt*A; within-chunk inclusive cumsum.
// ---------------------------------------------------------------------------
__global__ __launch_bounds__(256)
void dt_cumsum_kernel(const float* __restrict__ dtraw, const float* __restrict__ dt_bias,
                      const float* __restrict__ A_log, float* __restrict__ dtp,
                      float* __restrict__ csbuf)
{
  int h = blockIdx.x, cch = blockIdx.y, i = threadIdx.x;
  int t = cch * 256 + i;
  float x = dtraw[(size_t)t * 64 + h] + dt_bias[h];
  float sp = (x > 20.f) ? x : log1pf(expf(x));
  sp = fminf(fmaxf(sp, 0.f), 100.f);
  dtp[(size_t)t * 64 + h] = sp;
  float Ah = -expf(A_log[h]);
  __shared__ float s[256];
  s[i] = sp * Ah;
  __syncthreads();
  for (int off = 1; off < 256; off <<= 1) {
    float add = (i >= off) ? s[i - off] : 0.f;
    __syncthreads();
    s[i] += add;
    __syncthreads();
  }
  csbuf[(size_t)h * 4096 + t] = s[i];
}

// ---------------------------------------------------------------------------
// raw chunk scores[c][l][s] = sum_n C[l,n] B[s,n]
// ---------------------------------------------------------------------------
__global__ __launch_bounds__(256)
void scores_kernel(const __bf16* __restrict__ Cmat, const __bf16* __restrict__ Bmat,
                   __bf16* __restrict__ scores)
{
  const int c = blockIdx.x;
  const int lb = blockIdx.y * 128, sb = blockIdx.z * 128;
  const int tid = threadIdx.x, wave = tid >> 6, lane = tid & 63;
  const int quad = lane >> 4, l16 = lane & 15;
  const int wl = (wave & 1) * 64, ws = (wave >> 1) * 64;
  f32x4 acc[4][4] = {};
  for (int k = 0; k < 4; ++k) {
    bf16x8 af[4], bfr[4];
    for (int i = 0; i < 4; ++i) {
      int tl = c * 256 + lb + wl + i * 16 + l16;
      af[i] = *(const bf16x8*)(Cmat + (size_t)tl * 128 + k * 32 + quad * 8);
    }
    for (int j = 0; j < 4; ++j) {
      int ts = c * 256 + sb + ws + j * 16 + l16;
      bfr[j] = *(const bf16x8*)(Bmat + (size_t)ts * 128 + k * 32 + quad * 8);
    }
    for (int i = 0; i < 4; ++i)
      for (int j = 0; j < 4; ++j)
        acc[i][j] = __builtin_amdgcn_mfma_f32_16x16x32_bf16(af[i], bfr[j], acc[i][j], 0, 0, 0);
  }
  for (int i = 0; i < 4; ++i)
    for (int j = 0; j < 4; ++j) {
      int lrow = lb + wl + i * 16 + quad * 4;
      int scol = sb + ws + j * 16 + l16;
      for (int r = 0; r < 4; ++r)
        scores[((size_t)c * 256 + lrow + r) * 256 + scol] = (__bf16)acc[i][j][r];
    }
}

// ---------------------------------------------------------------------------
// chunk_states[c][h][p][n] = sum_l xdtT[h,p][l] * (B[l,n] * exp(cs_end - cs_l))
// ---------------------------------------------------------------------------
__global__ __launch_bounds__(256)
void states_kernel(const __bf16* __restrict__ xdtT, const __bf16* __restrict__ BTr,
                   const float* __restrict__ csbuf, __bf16* __restrict__ chunk_states)
{
  const int c = blockIdx.x, h = blockIdx.y;
  const int tid = threadIdx.x, wave = tid >> 6, lane = tid & 63;
  const int quad = lane >> 4, l16 = lane & 15;
  __shared__ float decay[256];
  {
    float cs_end = csbuf[(size_t)h * 4096 + c * 256 + 255];
    decay[tid] = expf(fminf(cs_end - csbuf[(size_t)h * 4096 + c * 256 + tid], 0.f));
  }
  __syncthreads();
  const int wn = wave * 32;
  f32x4 acc[4][2] = {};
  for (int k = 0; k < 8; ++k) {
    bf16x8 af[4], bfr[2];
    for (int i = 0; i < 4; ++i) {
      int p = i * 16 + l16;
      af[i] = *(const bf16x8*)(xdtT + (size_t)(h * 64 + p) * 4096 + c * 256 + k * 32 + quad * 8);
    }
    for (int j = 0; j < 2; ++j) {
      int n = wn + j * 16 + l16;
      bf16x8 raw = *(const bf16x8*)(BTr + (size_t)n * 4096 + c * 256 + k * 32 + quad * 8);
      bf16x8 sc;
      for (int jj = 0; jj < 8; ++jj)
        sc[jj] = (__bf16)((float)raw[jj] * decay[k * 32 + quad * 8 + jj]);
      bfr[j] = sc;
    }
    for (int i = 0; i < 4; ++i)
      for (int j = 0; j < 2; ++j)
        acc[i][j] = __builtin_amdgcn_mfma_f32_16x16x32_bf16(af[i], bfr[j], acc[i][j], 0, 0, 0);
  }
  for (int i = 0; i < 4; ++i)
    for (int j = 0; j < 2; ++j) {
      int p = i * 16 + quad * 4;
      int n = wn + j * 16 + l16;
      for (int r = 0; r < 4; ++r)
        chunk_states[(((size_t)c * 64 + h) * 64 + p + r) * 128 + n] = (__bf16)acc[i][j][r];
    }
}

// ---------------------------------------------------------------------------
// inter-chunk scan, IN-PLACE (states_in[c] overwrites chunk_states[c])
// ---------------------------------------------------------------------------
__global__ __launch_bounds__(256)
void scan_kernel(__bf16* states, const float* __restrict__ csbuf)
{
  size_t id = (size_t)blockIdx.x * 256 + threadIdx.x;  // 64*64*128
  int n = id & 127;
  int p = (int)((id >> 7) & 63);
  int h = (int)(id >> 13);
  float S = 0.f;
  for (int c = 0; c < 16; ++c) {
    size_t idx = (((size_t)c * 64 + h) * 64 + p) * 128 + n;
    float cst = (float)states[idx];
    states[idx] = (__bf16)S;
    float ce = csbuf[(size_t)h * 4096 + c * 256 + 255];
    S = S * expf(fminf(ce, 0.f)) + cst;
  }
}

// ---------------------------------------------------------------------------
// per (chunk, head): Y = exp(cs_l)*(C @ S_in^T) + (scores.decay.mask) @ xdt + x*D
// IN-PLACE: y holds xconv[t][hp] on entry; overwritten with the result.
// ---------------------------------------------------------------------------
__global__ __launch_bounds__(256)
void y_kernel(const __bf16* __restrict__ Cmat, const __bf16* __restrict__ states_in,
              const __bf16* __restrict__ scores, const __bf16* __restrict__ xdtT,
              const float* __restrict__ csbuf, const float* __restrict__ Dvec,
              __bf16* y)
{
  const int c = blockIdx.x, h = blockIdx.y;
  const int tid = threadIdx.x, wave = tid >> 6, lane = tid & 63;
  const int quad = lane >> 4, l16 = lane & 15;
  __shared__ float cs[256];
  cs[tid] = csbuf[(size_t)h * 4096 + c * 256 + tid];
  __syncthreads();
  const int wl = wave * 64;
  f32x4 acc[4][4] = {};

  // Y_off: A = C[l][n], B = states_in[c][h][p][n]
  for (int k = 0; k < 4; ++k) {
    bf16x8 af[4], bfr[4];
    for (int i = 0; i < 4; ++i) {
      int tl = c * 256 + wl + i * 16 + l16;
      af[i] = *(const bf16x8*)(Cmat + (size_t)tl * 128 + k * 32 + quad * 8);
    }
    for (int j = 0; j < 4; ++j) {
      int p = j * 16 + l16;
      bfr[j] = *(const bf16x8*)(states_in + (((size_t)c * 64 + h) * 64 + p) * 128 + k * 32 + quad * 8);
    }
    for (int i = 0; i < 4; ++i)
      for (int j = 0; j < 4; ++j)
        acc[i][j] = __builtin_amdgcn_mfma_f32_16x16x32_bf16(af[i], bfr[j], acc[i][j], 0, 0, 0);
  }
  for (int i = 0; i < 4; ++i)
    for (int r = 0; r < 4; ++r) {
      float sd = expf(fminf(cs[wl + i * 16 + quad * 4 + r], 0.f));
      for (int j = 0; j < 4; ++j) acc[i][j][r] *= sd;
    }
  // Y_diag: A = scores*decay*mask (built per fragment), B = xdtT
  for (int sb = 0; sb < 8; ++sb) {
    bf16x8 af[4], bfr[4];
    for (int i = 0; i < 4; ++i) {
      int lloc = wl + i * 16 + l16;
      bf16x8 raw = *(const bf16x8*)(scores + ((size_t)c * 256 + lloc) * 256 + sb * 32 + quad * 8);
      float csl = cs[lloc];
      bf16x8 w;
      for (int jj = 0; jj < 8; ++jj) {
        int s = sb * 32 + quad * 8 + jj;
        float e = expf(fminf(csl - cs[s], 0.f));
        float v = (s <= lloc) ? (float)raw[jj] * e : 0.f;
        w[jj] = (__bf16)v;
      }
      af[i] = w;
    }
    for (int j = 0; j < 4; ++j) {
      int p = j * 16 + l16;
      bfr[j] = *(const bf16x8*)(xdtT + (size_t)(h * 64 + p) * 4096 + c * 256 + sb * 32 + quad * 8);
    }
    for (int i = 0; i < 4; ++i)
      for (int j = 0; j < 4; ++j)
        acc[i][j] = __builtin_amdgcn_mfma_f32_16x16x32_bf16(af[i], bfr[j], acc[i][j], 0, 0, 0);
  }
  // epilogue: read x (in-place), add x*D, store
  float Dh = Dvec[h];
  for (int i = 0; i < 4; ++i)
    for (int r = 0; r < 4; ++r) {
      int tl = c * 256 + wl + i * 16 + quad * 4 + r;
      for (int j = 0; j < 4; ++j) {
        int p = j * 16 + l16;
        size_t idx = (size_t)tl * 4096 + h * 64 + p;
        float xv = (float)y[idx];
        y[idx] = (__bf16)(acc[i][j][r] + xv * Dh);
      }
    }
}

// ---------------------------------------------------------------------------
extern "C" void kernel_launch(void* const* d_in, const int* in_sizes, int n_in,
                              void* d_out, int out_size, void* d_ws, size_t ws_size,
                              hipStream_t stream)
{
  const float* hs      = (const float*)d_in[0];
  const float* W_in    = (const float*)d_in[1];
  const float* conv_w  = (const float*)d_in[2];
  const float* conv_b  = (const float*)d_in[3];
  const float* dt_bias = (const float*)d_in[4];
  const float* A_log   = (const float*)d_in[5];
  const float* Dv      = (const float*)d_in[6];
  const float* nw      = (const float*)d_in[7];
  const float* W_out   = (const float*)d_in[8];
  float* out = (float*)d_out;

  // Layout ~94.4 MB + d_out as xdtT scratch (dead before GEMM2 writes out).
  char* base = (char*)d_ws;
  const size_t P0 = 0;
  const size_t P1 = 35651584;
  const size_t P2 = 69206016;
  const size_t P3 = 77611008;

  __bf16* xBCraw  = (__bf16*)(base + P0);
  __bf16* states  = (__bf16*)(base + P0);
  __bf16* wTz     = (__bf16*)(base + P0);
  __bf16* wT_out  = (__bf16*)(base + P0 + 16777216);
  __bf16* wTa     = (__bf16*)(base + P1);
  __bf16* xconv   = (__bf16*)(base + P1);
  __bf16* Bmat    = (__bf16*)(base + P2);
  __bf16* Cmat    = (__bf16*)(base + P2 + 1048576);
  __bf16* BTr     = (__bf16*)(base + P2 + 2097152);
  float*  dtp     = (float*) (base + P2 + 3145728);
  float*  csbuf   = (float*) (base + P2 + 4194304);
  __bf16* scores  = (__bf16*)(base + P2 + 5242880);
  float*  dtraw   = (float*) (base + P2 + 7340032);
  float*  ssum    = (float*) (base + P2 + 8388608);   // 16KB
  __bf16* hs16    = (__bf16*)(base + P3);
  __bf16* xdtT    = (__bf16*)d_out;                    // 33.55MB scratch

  hipMemsetAsync(ssum, 0, 4096 * sizeof(float), stream);
  // 0. cast hs fp32 -> bf16
  cast_kernel<<<4096, 256, 0, stream>>>(hs, hs16);
  // 1. transpose+cast W_in cols [4096,8512) -> wTa[4416][2048]
  transpose_kernel<<<dim3(69, 32), 256, 0, stream>>>(W_in, wTa, 2048, 8512, 4096);
  // 2. GEMM1a wide-tile: xBC + dtraw (18 n-tiles of 256, masked edge)
  gemmw_kernel<0><<<dim3(18, 32), 256, 0, stream>>>(hs16, wTa, 4096, 4416, 2048, 2048,
                                                    xBCraw, dtraw, nullptr, nullptr, nullptr);
  // 3. dt softplus + cumsum (before conv: conv needs dtp)
  dt_cumsum_kernel<<<dim3(64, 16), 256, 0, stream>>>(dtraw, dt_bias, A_log, dtp, csbuf);
  // 4. FUSED conv + SiLU + xdtT/BTr transposes
  conv_fused_kernel<<<dim3(68, 64), 256, 0, stream>>>(xBCraw, conv_w, conv_b, dtp,
                                                      xconv, xdtT, Bmat, Cmat, BTr);
  // 5. chunk score matrices
  scores_kernel<<<dim3(16, 2, 2), 256, 0, stream>>>(Cmat, Bmat, scores);
  // 6. per-chunk states -> P0 (xBCraw dead)
  states_kernel<<<dim3(16, 64), 256, 0, stream>>>(xdtT, BTr, csbuf, states);
  // 7. inter-chunk scan in-place
  scan_kernel<<<2048, 256, 0, stream>>>(states, csbuf);
  // 8. y in-place over xconv
  y_kernel<<<dim3(16, 64), 256, 0, stream>>>(Cmat, states, scores, xdtT, csbuf, Dv, xconv);
  // 9. transpose+cast W_in cols [0,4096) -> wTz (states dead)
  transpose_kernel<<<dim3(64, 32), 256, 0, stream>>>(W_in, wTz, 2048, 8512, 0);
  // 10. z-GEMM wide-tile + gate, in-place on xconv, ssum
  gemmw_kernel<2><<<dim3(16, 32), 256, 0, stream>>>(hs16, wTz, 4096, 4096, 2048, 2048,
                                                    nullptr, nullptr, xconv, ssum, nw);
  // 11. transpose+cast W_out -> wT_out
  transpose_kernel<<<dim3(32, 64), 256, 0, stream>>>(W_out, wT_out, 4096, 2048, 0);
  // 12. GEMM2 128x128: plain fp32 store, per-row rsqrt scale (xdtT dead -> out)
  gemm_kernel<3><<<dim3(16, 32, 1), 256, 0, stream>>>(xconv, wT_out, 4096, 2048, 4096, 4096,
                                                      nullptr, out, ssum);
}

// Round 11
// 539.443 us; speedup vs baseline: 3.7949x; 1.0745x over previous
//
#include <hip/hip_runtime.h>
#include <hip/hip_bf16.h>
#include <math.h>

typedef __bf16 bf16x8 __attribute__((ext_vector_type(8)));
typedef float f32x4 __attribute__((ext_vector_type(4)));

#define GLOBAL_LOAD_LDS16(gptr, lptr) \
  __builtin_amdgcn_global_load_lds((const __attribute__((address_space(1))) void*)(gptr), \
                                   (__attribute__((address_space(3))) void*)(lptr), 16, 0, 0)

// XCD-aware bijective remap (m204) + GROUP_M=8 grouping: blocks resident on
// one XCD get a contiguous 2D patch of tiles -> A/B panels become L2 hits.
__device__ __forceinline__ void tile_map(int bid, int nbx, int nby, int& bx, int& by) {
  int nwg = nbx * nby;
  int q = nwg >> 3, r = nwg & 7;
  int xcd = bid & 7, orig = bid >> 3;
  int wgid = (xcd < r ? xcd * (q + 1) : r * (q + 1) + (xcd - r) * q) + orig;
  int per = nbx << 3;               // 8 M-rows per group
  int grp = wgid / per;
  int rem = wgid - grp * per;
  int g0 = grp << 3;
  int gm = nby - g0; if (gm > 8) gm = 8;
  by = g0 + rem % gm;               // m-fastest within group (B-panel reuse)
  bx = rem / gm;
}

// ---------------------------------------------------------------------------
// bf16 GEMM: C[M,N] = A[M,K] @ BT[N,K]^T. 128x128 tile, BK=64 single-buffered
// (32KB LDS) -> best measured structure (r6: 91us, 35% MfmaUtil; wide-tile
// 128x256 refuted in r10: 115us at 2 blocks/CU).
// LDS tile [128 rows][64 cols], 16B chunks xor-swizzled c^(r&7); stage source
// pre-swizzled so LDS dest stays linear. 0 bank conflicts measured.
// MODE 0: GEMM1a split epilogue (xBC bf16 stride 4352 | dt fp32 via out2)
// MODE 2: z-GEMM + gate: g = y*silu(z)*nw in-place into yio; ssum[t] += yf^2
// MODE 3: final GEMM, rows scaled by rsqrt(ssum/4096+eps), plain fp32 store
// ---------------------------------------------------------------------------
template<int MODE>
__global__ __launch_bounds__(256, 3)
void gemm_kernel(const __bf16* __restrict__ A, const __bf16* __restrict__ BT,
                 int M, int N, int K, int Ktot,
                 __bf16* __restrict__ out0, float* __restrict__ out2,
                 __bf16* yio, float* __restrict__ ssum,
                 const float* __restrict__ nwp)
{
  __shared__ __align__(16) __bf16 As[128 * 64];
  __shared__ __align__(16) __bf16 Bs[128 * 64];
  const int tid  = threadIdx.x;
  const int wave = tid >> 6, lane = tid & 63;
  const int quad = lane >> 4, l16 = lane & 15;
  int bx, by;
  tile_map(blockIdx.y * gridDim.x + blockIdx.x, gridDim.x, gridDim.y, bx, by);
  const int mBase = by * 128;
  const int nBase = bx * 128;
  const int wm = (wave & 1) * 64;
  const int wn = (wave >> 1) * 64;

  f32x4 acc[4][4] = {};

  for (int k0 = 0; k0 < K; k0 += 64) {
    __syncthreads();                          // previous iter's ds_reads done
    for (int rd = 0; rd < 4; ++rd) {
      int p = rd * 256 + tid;                 // phys 16B chunk 0..1023
      int row = p >> 3;                       // 0..127
      int lc  = (p & 7) ^ (row & 7);          // logical chunk this slot holds
      const __bf16* gpA = A + (size_t)(mBase + row) * Ktot + k0 + lc * 8;
      GLOBAL_LOAD_LDS16(gpA, As + rd * 2048 + wave * 512);
      int gr = nBase + row; if (gr >= N) gr = N - 1;   // clamp (epilogue masks)
      const __bf16* gpB = BT + (size_t)gr * Ktot + k0 + lc * 8;
      GLOBAL_LOAD_LDS16(gpB, Bs + rd * 2048 + wave * 512);
    }
    __syncthreads();                          // drains vmcnt (compiler-emitted)
#pragma unroll
    for (int ks = 0; ks < 2; ++ks) {
      bf16x8 af[4], bfr[4];
#pragma unroll
      for (int i = 0; i < 4; ++i) {
        int r = wm + i * 16 + l16;
        af[i]  = *(const bf16x8*)(As + (r << 6) + (((ks * 4 + quad) ^ (r & 7)) << 3));
        int rb = wn + i * 16 + l16;
        bfr[i] = *(const bf16x8*)(Bs + (rb << 6) + (((ks * 4 + quad) ^ (rb & 7)) << 3));
      }
#pragma unroll
      for (int i = 0; i < 4; ++i)
#pragma unroll
        for (int j = 0; j < 4; ++j)
          acc[i][j] = __builtin_amdgcn_mfma_f32_16x16x32_bf16(af[i], bfr[j], acc[i][j], 0, 0, 0);
    }
  }

  // epilogue: C/D layout col = lane&15, row = quad*4 + r
  // ALL acc-indexing loops unrolled (rule #20: no runtime indexing).
  if (MODE == 2) {
#pragma unroll
    for (int i = 0; i < 4; ++i)
#pragma unroll
      for (int r = 0; r < 4; ++r) {
        int row = mBase + wm + i * 16 + quad * 4 + r;
        float sq = 0.f;
#pragma unroll
        for (int j = 0; j < 4; ++j) {
          int col = nBase + wn + j * 16 + l16;
          float v = acc[i][j][r];
          size_t idx = (size_t)row * 4096 + col;
          float y0 = (float)yio[idx];
          float zg = v / (1.f + __expf(-v));  // silu(z), fast exp
          float yf = y0 * zg;
          yio[idx] = (__bf16)(yf * nwp[col]);
          sq += yf * yf;
        }
#pragma unroll
        for (int m = 1; m < 16; m <<= 1) sq += __shfl_xor(sq, m, 64);
        if (l16 == 0) atomicAdd(&ssum[row], sq);
      }
  } else if (MODE == 3) {
#pragma unroll
    for (int i = 0; i < 4; ++i) {
#pragma unroll
      for (int j = 0; j < 4; ++j) {
        int col = nBase + wn + j * 16 + l16;
#pragma unroll
        for (int r = 0; r < 4; ++r) {
          int row = mBase + wm + i * 16 + quad * 4 + r;
          float s = rsqrtf(ssum[row] / 4096.f + 1e-5f);
          float o = acc[i][j][r] * s;
          o = (o == o && fabsf(o) < 1e30f) ? o : 0.f;
          out2[(size_t)row * N + col] = o;
        }
      }
    }
  } else {
#pragma unroll
    for (int i = 0; i < 4; ++i) {
      int rowl = wm + i * 16 + quad * 4;
#pragma unroll
      for (int j = 0; j < 4; ++j) {
        int col = nBase + wn + j * 16 + l16;
#pragma unroll
        for (int r = 0; r < 4; ++r) {
          float v = acc[i][j][r];
          int row = mBase + rowl + r;
          if (col < 4352)       out0[(size_t)row * 4352 + col]        = (__bf16)v;
          else if (col < 4416)  out2[(size_t)row * 64 + (col - 4352)] = v;
        }
      }
    }
  }
}

// ---------------------------------------------------------------------------
// fp32 -> bf16 cast: vector f32x4 loads + one bf16x8 store
// ---------------------------------------------------------------------------
__global__ __launch_bounds__(256)
void cast_kernel(const float* __restrict__ in, __bf16* __restrict__ out)
{
  size_t g = ((size_t)blockIdx.x * 256 + threadIdx.x) * 8;
  f32x4 a = *(const f32x4*)(in + g);
  f32x4 b = *(const f32x4*)(in + g + 4);
  bf16x8 v;
  for (int j = 0; j < 4; ++j) { v[j] = (__bf16)a[j]; v[4 + j] = (__bf16)b[j]; }
  *(bf16x8*)(out + g) = v;
}

// ---------------------------------------------------------------------------
// fp32 transpose+cast: out[c][r] = (bf16)in[r][col0+c]. Vector loads/stores.
// ---------------------------------------------------------------------------
__global__ __launch_bounds__(256)
void transpose_kernel(const float* __restrict__ in, __bf16* __restrict__ out,
                      int R, int C, int col0)
{
  __shared__ __bf16 tile[64][72];
  const int tid = threadIdx.x;
  const int r0 = blockIdx.y * 64, c0 = blockIdx.x * 64;
  const int tr = tid >> 3, tc = (tid & 7) * 8;   // tr 0..31
  for (int hh = 0; hh < 2; ++hh) {
    const float* gp = in + (size_t)(r0 + tr + hh * 32) * C + col0 + c0 + tc;
    f32x4 a = *(const f32x4*)gp;
    f32x4 b = *(const f32x4*)(gp + 4);
    for (int j = 0; j < 4; ++j) {
      tile[tr + hh * 32][tc + j]     = (__bf16)a[j];
      tile[tr + hh * 32][tc + 4 + j] = (__bf16)b[j];
    }
  }
  __syncthreads();
  for (int hh = 0; hh < 2; ++hh) {
    __bf16* op = out + (size_t)(c0 + tr + hh * 32) * R + r0 + tc;
    bf16x8 o;
    for (int j = 0; j < 8; ++j) o[j] = tile[tc + j][tr + hh * 32];
    *(bf16x8*)op = o;
  }
}

// ---------------------------------------------------------------------------
// FUSED causal conv1d (K=4) + bias + SiLU + routing + transposes.
// Grid (68 c-tiles x 64 t-tiles), 64x64 tile per block, 2 rows/thread.
//  bx<64 : x-region -> xconv[t][c] AND xdtT[c][t] = x*dtp via LDS
//  bx=64,65: B-region -> Bmat[t][n] AND BTr[n][t] via LDS
//  bx=66,67: C-region -> Cmat[t][n]
// ---------------------------------------------------------------------------
__global__ __launch_bounds__(256)
void conv_fused_kernel(const __bf16* __restrict__ xBCraw, const float* __restrict__ conv_w,
                       const float* __restrict__ conv_b, const float* __restrict__ dtp,
                       __bf16* __restrict__ xconv, __bf16* __restrict__ xdtT,
                       __bf16* __restrict__ Bmat, __bf16* __restrict__ Cmat,
                       __bf16* __restrict__ BTr)
{
  __shared__ __bf16 tile[64][72];
  const int bx = blockIdx.x;                  // c-tile 0..67
  const int t0 = blockIdx.y * 64;
  const int tid = threadIdx.x;
  const int tr = tid >> 3, tc = (tid & 7) * 8;
  const int cc = bx * 64 + tc;                // global conv col

  float wgt[4][8], bias[8];
  {
    f32x4 b0 = *(const f32x4*)(conv_b + cc);
    f32x4 b1 = *(const f32x4*)(conv_b + cc + 4);
    for (int j = 0; j < 4; ++j) { bias[j] = b0[j]; bias[4 + j] = b1[j]; }
    for (int k = 0; k < 4; ++k) {
      f32x4 w0 = *(const f32x4*)(conv_w + (size_t)k * 4352 + cc);
      f32x4 w1 = *(const f32x4*)(conv_w + (size_t)k * 4352 + cc + 4);
      for (int j = 0; j < 4; ++j) { wgt[k][j] = w0[j]; wgt[k][4 + j] = w1[j]; }
    }
  }

  for (int hh = 0; hh < 2; ++hh) {
    int t = t0 + tr + hh * 32;
    float acc[8];
    for (int j = 0; j < 8; ++j) acc[j] = bias[j];
    for (int k = 0; k < 4; ++k) {
      int ts = t + k - 3;
      if (ts >= 0) {
        bf16x8 xv = *(const bf16x8*)(xBCraw + (size_t)ts * 4352 + cc);
        for (int j = 0; j < 8; ++j) acc[j] += (float)xv[j] * wgt[k][j];
      }
    }
    for (int j = 0; j < 8; ++j) { float v = acc[j]; acc[j] = v / (1.f + __expf(-v)); }
    bf16x8 o;
    for (int j = 0; j < 8; ++j) o[j] = (__bf16)acc[j];
    if (bx < 64) {
      *(bf16x8*)(xconv + (size_t)t * 4096 + cc) = o;
      float ds = dtp[(size_t)t * 64 + bx];    // h == bx (tile 64-aligned)
      for (int j = 0; j < 8; ++j) tile[tr + hh * 32][tc + j] = (__bf16)(acc[j] * ds);
    } else if (bx < 66) {
      *(bf16x8*)(Bmat + (size_t)t * 128 + (cc - 4096)) = o;
      for (int j = 0; j < 8; ++j) tile[tr + hh * 32][tc + j] = o[j];
    } else {
      *(bf16x8*)(Cmat + (size_t)t * 128 + (cc - 4224)) = o;
    }
  }
  __syncthreads();
  if (bx < 64) {
    for (int hh = 0; hh < 2; ++hh) {
      __bf16* op = xdtT + (size_t)(bx * 64 + tr + hh * 32) * 4096 + t0 + tc;
      bf16x8 o;
      for (int j = 0; j < 8; ++j) o[j] = tile[tc + j][tr + hh * 32];
      *(bf16x8*)op = o;
    }
  } else if (bx < 66) {
    for (int hh = 0; hh < 2; ++hh) {
      __bf16* op = BTr + (size_t)((bx - 64) * 64 + tr + hh * 32) * 4096 + t0 + tc;
      bf16x8 o;
      for (int j = 0; j < 8; ++j) o[j] = tile[tc + j][tr + hh * 32];
      *(bf16x8*)op = o;
    }
  }
}

// ---------------------------------------------------------------------------
// dt = clip(softplus(dtraw + bias)); dA = dt*A; within-chunk inclusive cumsum.
// (kept in precise expf: feeds every decay exponent downstream)
// ---------------------------------------------------------------------------
__global__ __launch_bounds__(256)
void dt_cumsum_kernel(const float* __restrict__ dtraw, const float* __restrict__ dt_bias,
                      const float* __restrict__ A_log, float* __restrict__ dtp,
                      float* __restrict__ csbuf)
{
  int h = blockIdx.x, cch = blockIdx.y, i = threadIdx.x;
  int t = cch * 256 + i;
  float x = dtraw[(size_t)t * 64 + h] + dt_bias[h];
  float sp = (x > 20.f) ? x : log1pf(expf(x));
  sp = fminf(fmaxf(sp, 0.f), 100.f);
  dtp[(size_t)t * 64 + h] = sp;
  float Ah = -expf(A_log[h]);
  __shared__ float s[256];
  s[i] = sp * Ah;
  __syncthreads();
  for (int off = 1; off < 256; off <<= 1) {
    float add = (i >= off) ? s[i - off] : 0.f;
    __syncthreads();
    s[i] += add;
    __syncthreads();
  }
  csbuf[(size_t)h * 4096 + t] = s[i];
}

// ---------------------------------------------------------------------------
// raw chunk scores[c][l][s] = sum_n C[l,n] B[s,n]
// ---------------------------------------------------------------------------
__global__ __launch_bounds__(256)
void scores_kernel(const __bf16* __restrict__ Cmat, const __bf16* __restrict__ Bmat,
                   __bf16* __restrict__ scores)
{
  const int c = blockIdx.x;
  const int lb = blockIdx.y * 128, sb = blockIdx.z * 128;
  const int tid = threadIdx.x, wave = tid >> 6, lane = tid & 63;
  const int quad = lane >> 4, l16 = lane & 15;
  const int wl = (wave & 1) * 64, ws = (wave >> 1) * 64;
  f32x4 acc[4][4] = {};
  for (int k = 0; k < 4; ++k) {
    bf16x8 af[4], bfr[4];
    for (int i = 0; i < 4; ++i) {
      int tl = c * 256 + lb + wl + i * 16 + l16;
      af[i] = *(const bf16x8*)(Cmat + (size_t)tl * 128 + k * 32 + quad * 8);
    }
    for (int j = 0; j < 4; ++j) {
      int ts = c * 256 + sb + ws + j * 16 + l16;
      bfr[j] = *(const bf16x8*)(Bmat + (size_t)ts * 128 + k * 32 + quad * 8);
    }
    for (int i = 0; i < 4; ++i)
      for (int j = 0; j < 4; ++j)
        acc[i][j] = __builtin_amdgcn_mfma_f32_16x16x32_bf16(af[i], bfr[j], acc[i][j], 0, 0, 0);
  }
  for (int i = 0; i < 4; ++i)
    for (int j = 0; j < 4; ++j) {
      int lrow = lb + wl + i * 16 + quad * 4;
      int scol = sb + ws + j * 16 + l16;
      for (int r = 0; r < 4; ++r)
        scores[((size_t)c * 256 + lrow + r) * 256 + scol] = (__bf16)acc[i][j][r];
    }
}

// ---------------------------------------------------------------------------
// chunk_states[c][h][p][n] = sum_l xdtT[h,p][l] * (B[l,n] * exp(cs_end - cs_l))
// ---------------------------------------------------------------------------
__global__ __launch_bounds__(256)
void states_kernel(const __bf16* __restrict__ xdtT, const __bf16* __restrict__ BTr,
                   const float* __restrict__ csbuf, __bf16* __restrict__ chunk_states)
{
  const int c = blockIdx.x, h = blockIdx.y;
  const int tid = threadIdx.x, wave = tid >> 6, lane = tid & 63;
  const int quad = lane >> 4, l16 = lane & 15;
  __shared__ float decay[256];
  {
    float cs_end = csbuf[(size_t)h * 4096 + c * 256 + 255];
    decay[tid] = __expf(fminf(cs_end - csbuf[(size_t)h * 4096 + c * 256 + tid], 0.f));
  }
  __syncthreads();
  const int wn = wave * 32;
  f32x4 acc[4][2] = {};
  for (int k = 0; k < 8; ++k) {
    bf16x8 af[4], bfr[2];
    for (int i = 0; i < 4; ++i) {
      int p = i * 16 + l16;
      af[i] = *(const bf16x8*)(xdtT + (size_t)(h * 64 + p) * 4096 + c * 256 + k * 32 + quad * 8);
    }
    for (int j = 0; j < 2; ++j) {
      int n = wn + j * 16 + l16;
      bf16x8 raw = *(const bf16x8*)(BTr + (size_t)n * 4096 + c * 256 + k * 32 + quad * 8);
      bf16x8 sc;
      for (int jj = 0; jj < 8; ++jj)
        sc[jj] = (__bf16)((float)raw[jj] * decay[k * 32 + quad * 8 + jj]);
      bfr[j] = sc;
    }
    for (int i = 0; i < 4; ++i)
      for (int j = 0; j < 2; ++j)
        acc[i][j] = __builtin_amdgcn_mfma_f32_16x16x32_bf16(af[i], bfr[j], acc[i][j], 0, 0, 0);
  }
  for (int i = 0; i < 4; ++i)
    for (int j = 0; j < 2; ++j) {
      int p = i * 16 + quad * 4;
      int n = wn + j * 16 + l16;
      for (int r = 0; r < 4; ++r)
        chunk_states[(((size_t)c * 64 + h) * 64 + p + r) * 128 + n] = (__bf16)acc[i][j][r];
    }
}

// ---------------------------------------------------------------------------
// inter-chunk scan, IN-PLACE (states_in[c] overwrites chunk_states[c])
// ---------------------------------------------------------------------------
__global__ __launch_bounds__(256)
void scan_kernel(__bf16* states, const float* __restrict__ csbuf)
{
  size_t id = (size_t)blockIdx.x * 256 + threadIdx.x;  // 64*64*128
  int n = id & 127;
  int p = (int)((id >> 7) & 63);
  int h = (int)(id >> 13);
  float S = 0.f;
  for (int c = 0; c < 16; ++c) {
    size_t idx = (((size_t)c * 64 + h) * 64 + p) * 128 + n;
    float cst = (float)states[idx];
    states[idx] = (__bf16)S;
    float ce = csbuf[(size_t)h * 4096 + c * 256 + 255];
    S = S * __expf(fminf(ce, 0.f)) + cst;
  }
}

// ---------------------------------------------------------------------------
// per (chunk, head): Y = exp(cs_l)*(C @ S_in^T) + (scores.decay.mask) @ xdt + x*D
// IN-PLACE: y holds xconv[t][hp] on entry; overwritten with the result.
// __expf throughout: 256+ exps/thread in the Y_diag mask build were a major
// VALU cost with precise expf.
// ---------------------------------------------------------------------------
__global__ __launch_bounds__(256)
void y_kernel(const __bf16* __restrict__ Cmat, const __bf16* __restrict__ states_in,
              const __bf16* __restrict__ scores, const __bf16* __restrict__ xdtT,
              const float* __restrict__ csbuf, const float* __restrict__ Dvec,
              __bf16* y)
{
  const int c = blockIdx.x, h = blockIdx.y;
  const int tid = threadIdx.x, wave = tid >> 6, lane = tid & 63;
  const int quad = lane >> 4, l16 = lane & 15;
  __shared__ float cs[256];
  cs[tid] = csbuf[(size_t)h * 4096 + c * 256 + tid];
  __syncthreads();
  const int wl = wave * 64;
  f32x4 acc[4][4] = {};

  // Y_off: A = C[l][n], B = states_in[c][h][p][n]
  for (int k = 0; k < 4; ++k) {
    bf16x8 af[4], bfr[4];
    for (int i = 0; i < 4; ++i) {
      int tl = c * 256 + wl + i * 16 + l16;
      af[i] = *(const bf16x8*)(Cmat + (size_t)tl * 128 + k * 32 + quad * 8);
    }
    for (int j = 0; j < 4; ++j) {
      int p = j * 16 + l16;
      bfr[j] = *(const bf16x8*)(states_in + (((size_t)c * 64 + h) * 64 + p) * 128 + k * 32 + quad * 8);
    }
    for (int i = 0; i < 4; ++i)
      for (int j = 0; j < 4; ++j)
        acc[i][j] = __builtin_amdgcn_mfma_f32_16x16x32_bf16(af[i], bfr[j], acc[i][j], 0, 0, 0);
  }
  for (int i = 0; i < 4; ++i)
    for (int r = 0; r < 4; ++r) {
      float sd = __expf(fminf(cs[wl + i * 16 + quad * 4 + r], 0.f));
      for (int j = 0; j < 4; ++j) acc[i][j][r] *= sd;
    }
  // Y_diag: A = scores*decay*mask (built per fragment), B = xdtT
  for (int sb = 0; sb < 8; ++sb) {
    bf16x8 af[4], bfr[4];
    for (int i = 0; i < 4; ++i) {
      int lloc = wl + i * 16 + l16;
      bf16x8 raw = *(const bf16x8*)(scores + ((size_t)c * 256 + lloc) * 256 + sb * 32 + quad * 8);
      float csl = cs[lloc];
      bf16x8 w;
      for (int jj = 0; jj < 8; ++jj) {
        int s = sb * 32 + quad * 8 + jj;
        float e = __expf(fminf(csl - cs[s], 0.f));
        float v = (s <= lloc) ? (float)raw[jj] * e : 0.f;
        w[jj] = (__bf16)v;
      }
      af[i] = w;
    }
    for (int j = 0; j < 4; ++j) {
      int p = j * 16 + l16;
      bfr[j] = *(const bf16x8*)(xdtT + (size_t)(h * 64 + p) * 4096 + c * 256 + sb * 32 + quad * 8);
    }
    for (int i = 0; i < 4; ++i)
      for (int j = 0; j < 4; ++j)
        acc[i][j] = __builtin_amdgcn_mfma_f32_16x16x32_bf16(af[i], bfr[j], acc[i][j], 0, 0, 0);
  }
  // epilogue: read x (in-place), add x*D, store
  float Dh = Dvec[h];
  for (int i = 0; i < 4; ++i)
    for (int r = 0; r < 4; ++r) {
      int tl = c * 256 + wl + i * 16 + quad * 4 + r;
      for (int j = 0; j < 4; ++j) {
        int p = j * 16 + l16;
        size_t idx = (size_t)tl * 4096 + h * 64 + p;
        float xv = (float)y[idx];
        y[idx] = (__bf16)(acc[i][j][r] + xv * Dh);
      }
    }
}

// ---------------------------------------------------------------------------
extern "C" void kernel_launch(void* const* d_in, const int* in_sizes, int n_in,
                              void* d_out, int out_size, void* d_ws, size_t ws_size,
                              hipStream_t stream)
{
  const float* hs      = (const float*)d_in[0];
  const float* W_in    = (const float*)d_in[1];
  const float* conv_w  = (const float*)d_in[2];
  const float* conv_b  = (const float*)d_in[3];
  const float* dt_bias = (const float*)d_in[4];
  const float* A_log   = (const float*)d_in[5];
  const float* Dv      = (const float*)d_in[6];
  const float* nw      = (const float*)d_in[7];
  const float* W_out   = (const float*)d_in[8];
  float* out = (float*)d_out;

  // Layout ~94.4 MB + d_out as xdtT scratch (dead before GEMM2 writes out).
  char* base = (char*)d_ws;
  const size_t P0 = 0;
  const size_t P1 = 35651584;
  const size_t P2 = 69206016;
  const size_t P3 = 77611008;

  __bf16* xBCraw  = (__bf16*)(base + P0);
  __bf16* states  = (__bf16*)(base + P0);
  __bf16* wTz     = (__bf16*)(base + P0);
  __bf16* wT_out  = (__bf16*)(base + P0 + 16777216);
  __bf16* wTa     = (__bf16*)(base + P1);
  __bf16* xconv   = (__bf16*)(base + P1);
  __bf16* Bmat    = (__bf16*)(base + P2);
  __bf16* Cmat    = (__bf16*)(base + P2 + 1048576);
  __bf16* BTr     = (__bf16*)(base + P2 + 2097152);
  float*  dtp     = (float*) (base + P2 + 3145728);
  float*  csbuf   = (float*) (base + P2 + 4194304);
  __bf16* scores  = (__bf16*)(base + P2 + 5242880);
  float*  dtraw   = (float*) (base + P2 + 7340032);
  float*  ssum    = (float*) (base + P2 + 8388608);   // 16KB
  __bf16* hs16    = (__bf16*)(base + P3);
  __bf16* xdtT    = (__bf16*)d_out;                    // 33.55MB scratch

  hipMemsetAsync(ssum, 0, 4096 * sizeof(float), stream);
  // 0. cast hs fp32 -> bf16
  cast_kernel<<<4096, 256, 0, stream>>>(hs, hs16);
  // 1. transpose+cast W_in cols [4096,8512) -> wTa[4416][2048]
  transpose_kernel<<<dim3(69, 32), 256, 0, stream>>>(W_in, wTa, 2048, 8512, 4096);
  // 2. GEMM1a 128x128 BK=64 (proven): xBC + dtraw
  gemm_kernel<0><<<dim3(35, 32), 256, 0, stream>>>(hs16, wTa, 4096, 4416, 2048, 2048,
                                                   xBCraw, dtraw, nullptr, nullptr, nullptr);
  // 3. dt softplus + cumsum (before conv: conv needs dtp)
  dt_cumsum_kernel<<<dim3(64, 16), 256, 0, stream>>>(dtraw, dt_bias, A_log, dtp, csbuf);
  // 4. FUSED conv + SiLU + xdtT/BTr transposes
  conv_fused_kernel<<<dim3(68, 64), 256, 0, stream>>>(xBCraw, conv_w, conv_b, dtp,
                                                      xconv, xdtT, Bmat, Cmat, BTr);
  // 5. chunk score matrices
  scores_kernel<<<dim3(16, 2, 2), 256, 0, stream>>>(Cmat, Bmat, scores);
  // 6. per-chunk states -> P0 (xBCraw dead)
  states_kernel<<<dim3(16, 64), 256, 0, stream>>>(xdtT, BTr, csbuf, states);
  // 7. inter-chunk scan in-place
  scan_kernel<<<2048, 256, 0, stream>>>(states, csbuf);
  // 8. y in-place over xconv
  y_kernel<<<dim3(16, 64), 256, 0, stream>>>(Cmat, states, scores, xdtT, csbuf, Dv, xconv);
  // 9. transpose+cast W_in cols [0,4096) -> wTz (states dead)
  transpose_kernel<<<dim3(64, 32), 256, 0, stream>>>(W_in, wTz, 2048, 8512, 0);
  // 10. z-GEMM 128x128 BK=64 (proven) + gate, in-place on xconv, ssum
  gemm_kernel<2><<<dim3(32, 32), 256, 0, stream>>>(hs16, wTz, 4096, 4096, 2048, 2048,
                                                   nullptr, nullptr, xconv, ssum, nw);
  // 11. transpose+cast W_out -> wT_out
  transpose_kernel<<<dim3(32, 64), 256, 0, stream>>>(W_out, wT_out, 4096, 2048, 0);
  // 12. GEMM2 128x128: plain fp32 store, per-row rsqrt scale (xdtT dead -> out)
  gemm_kernel<3><<<dim3(16, 32, 1), 256, 0, stream>>>(xconv, wT_out, 4096, 2048, 4096, 4096,
                                                      nullptr, out, nullptr, ssum, nullptr);
}